// Round 3
// baseline (298.946 us; speedup 1.0000x reference)
//
#include <hip/hip_runtime.h>
#include <hip/hip_bf16.h>
#include <stdint.h>

// B=16, N=4096, H=512, K=2H=1024
//   pf[b,n,h]   = sum_k features[b,n,k] * Wf[h,k]
//   pq[b,h]     = sum_k query[b,k] * Wq[h,k]
//   logits[b,n] = 10*tanh( sum_h v[h]*tanh(pf+pq) )
// Outputs: pf (33554432 f32) then logits (65536 f32).
// R3 = R2 design with ws shrunk below the proven-safe 1.08MB (suspected R2
// crash cause: ws overflow from the 1MB upart buffer). Cross-wave u-reduction
// now happens in LDS inside the gemm epilogue; finish kernel removed.
//   - Wf pre-converted to bf16 once (1MB ws)
//   - B staged via global_load_lds, inverse-swizzled per-lane global sources
//   - A direct global->reg (4x wn redundancy served by L1), cvt_pk to bf16
//   - counted s_waitcnt vmcnt(12) + raw s_barrier (loads in flight across
//     barriers, no vmcnt(0) drain in the main loop)

#define MROWS 65536
#define KDIM  1024
#define HDIM  512

typedef short bf16x8 __attribute__((ext_vector_type(8)));
typedef float f32x4  __attribute__((ext_vector_type(4)));

__device__ __forceinline__ float fast_tanh(float x) {
    float ax = fabsf(x);
    float e  = __expf(-2.0f * ax);
    float r  = (1.0f - e) / (1.0f + e);
    return copysignf(r, x);
}

__device__ __forceinline__ short f2bf(float x) {
    __hip_bfloat16 b = __float2bfloat16(x);
    return (short)__builtin_bit_cast(unsigned short, b);
}

__device__ __forceinline__ bf16x8 cvt8(float4 a, float4 b) {
    bf16x8 o;
    o[0] = f2bf(a.x); o[1] = f2bf(a.y); o[2] = f2bf(a.z); o[3] = f2bf(a.w);
    o[4] = f2bf(b.x); o[5] = f2bf(b.y); o[6] = f2bf(b.z); o[7] = f2bf(b.w);
    return o;
}

// ---------------- Wf fp32 -> bf16 (once) ----------------
__global__ void wfcvt_kernel(const float* __restrict__ Wf, short* __restrict__ out) {
    const int i = (blockIdx.x * 256 + threadIdx.x) * 8;
    float4 a = *(const float4*)(Wf + i);
    float4 b = *(const float4*)(Wf + i + 4);
    *(bf16x8*)(out + i) = cvt8(a, b);
}

// ---------------- tiny GEMM: pq[b,h] ----------------
__global__ void pq_kernel(const float* __restrict__ query,
                          const float* __restrict__ Wq,
                          float* __restrict__ pq) {
    const int t = blockIdx.x * blockDim.x + threadIdx.x;   // 8192
    const int b = t >> 9, h = t & 511;
    const float4* q  = (const float4*)(query + (b << 9));
    const float4* wq = (const float4*)(Wq + ((size_t)h << 9));
    float s = 0.0f;
    #pragma unroll 4
    for (int i = 0; i < 128; ++i) {
        float4 a = q[i], c = wq[i];
        s += a.x * c.x + a.y * c.y + a.z * c.z + a.w * c.w;
    }
    pq[t] = s;
}

// ---------------- main GEMM + fused epilogue ----------------
// 512 threads = 8 waves (2m x 4n), tile 128x512, BK=32, 32 K-steps.
__global__ __launch_bounds__(512, 2) void gemm_kernel(
    const float* __restrict__ A, const short* __restrict__ Wbf,
    const float* __restrict__ pq, const float* __restrict__ v,
    float* __restrict__ pf, float* __restrict__ logits)
{
    __shared__ __align__(16) char ldsB[2][32768];
    const int t    = threadIdx.x;
    const int lane = t & 63;
    const int w    = t >> 6;
    const int wm   = w >> 2;
    const int wn   = w & 3;
    const int Mbase = blockIdx.x * 128;
    const int fm = lane & 15;
    const int fk = (lane >> 4) * 8;            // k offset in elems

    // ---- B staging: inverse-swizzled per-lane global source ----
    // Read-side layout: addr(h,kb) = h*64 + (kb ^ ((h&7)<<4)); the XOR's bit6
    // crosses into the row field, so the inverse decodes h from bits 7.. plus
    // a bit6^bit8 correction, then un-XORs bits 4-5 of kb.
    const char* Wb = (const char*)Wbf;
    int woff[4];
    #pragma unroll
    for (int p = 0; p < 4; ++p) {
        const int c  = (p * 8 + w) * 1024 + lane * 16;
        const int h2 = (c >> 8) & 1;
        const int h  = ((c >> 7) << 1) | (((c >> 6) & 1) ^ h2);
        const int kb = (c & 63) ^ ((h & 3) << 4);
        woff[p] = h * 2048 + kb;               // byte offset in Wbf
    }

    // ---- A direct-load offsets (float index) ----
    int aoff[4];
    #pragma unroll
    for (int f = 0; f < 4; ++f)
        aoff[f] = (Mbase + wm * 64 + f * 16 + fm) * KDIM + fk;

    // ---- B fragment read offset (swizzled) ----
    const int bconst = wn * 8192 + ((fm * 64 + fk * 2) ^ ((fm & 7) << 4));

    f32x4 acc[4][8];
    const f32x4 zf = {0.0f, 0.0f, 0.0f, 0.0f};
    #pragma unroll
    for (int f = 0; f < 4; ++f)
        #pragma unroll
        for (int g = 0; g < 8; ++g) acc[f][g] = zf;

    float4 aX[8], aY[8];
    bf16x8 abf[4], bfr[8];

    #define STAGE_B(BUF, kt) do {                                            \
        _Pragma("unroll")                                                    \
        for (int p = 0; p < 4; ++p)                                          \
            __builtin_amdgcn_global_load_lds(                                \
                (const __attribute__((address_space(1))) void*)              \
                    (Wb + woff[p] + (kt) * 64),                              \
                (__attribute__((address_space(3))) void*)                    \
                    (&ldsB[BUF][(p * 8 + w) * 1024]),                        \
                16, 0, 0);                                                   \
    } while (0)

    #define LOAD_A(dst, kt) do {                                             \
        _Pragma("unroll")                                                    \
        for (int f = 0; f < 4; ++f) {                                        \
            const float4* ap = (const float4*)(A + aoff[f]) + (kt) * 8;      \
            dst[2 * f]     = ap[0];                                          \
            dst[2 * f + 1] = ap[1];                                          \
        }                                                                    \
    } while (0)

    #define KBODY(kt, CUR, ACUR, ANXT) do {                                  \
        if ((kt) < 31) { STAGE_B(CUR ^ 1, (kt) + 1); LOAD_A(ANXT, (kt) + 1); } \
        _Pragma("unroll")                                                    \
        for (int f = 0; f < 4; ++f) abf[f] = cvt8(ACUR[2*f], ACUR[2*f+1]);   \
        if ((kt) < 31) asm volatile("s_waitcnt vmcnt(12)" ::: "memory");     \
        else           asm volatile("s_waitcnt vmcnt(0)"  ::: "memory");     \
        __builtin_amdgcn_s_barrier();                                        \
        asm volatile("" ::: "memory");                                       \
        _Pragma("unroll")                                                    \
        for (int g = 0; g < 8; ++g)                                          \
            bfr[g] = *(const bf16x8*)(&ldsB[CUR][bconst + g * 1024]);        \
        _Pragma("unroll")                                                    \
        for (int f = 0; f < 4; ++f)                                          \
            _Pragma("unroll")                                                \
            for (int g = 0; g < 8; ++g)                                      \
                acc[f][g] = __builtin_amdgcn_mfma_f32_16x16x32_bf16(         \
                    abf[f], bfr[g], acc[f][g], 0, 0, 0);                     \
        asm volatile("" ::: "memory");                                       \
        __builtin_amdgcn_s_barrier();                                        \
        asm volatile("" ::: "memory");                                       \
    } while (0)

    STAGE_B(0, 0);
    LOAD_A(aX, 0);

    #pragma unroll 1
    for (int kt2 = 0; kt2 < 16; ++kt2) {
        KBODY(2 * kt2,     0, aX, aY);
        KBODY(2 * kt2 + 1, 1, aY, aX);
    }

    // ---- fused epilogue: pf store + u partials into LDS ----
    float* uls = (float*)&ldsB[0][0];          // 128 rows x 4 wn slots (2KB)
    const int bidx = Mbase >> 12;
    const float* pqb = pq + (bidx << 9);
    float vv[8], pv[8];
    #pragma unroll
    for (int g = 0; g < 8; ++g) {
        const int c = wn * 128 + g * 16 + fm;
        vv[g] = v[c];
        pv[g] = pqb[c];
    }
    const int rq = (lane >> 4) * 4;
    #pragma unroll
    for (int f = 0; f < 4; ++f) {
        #pragma unroll
        for (int rr = 0; rr < 4; ++rr) {
            const int rloc = wm * 64 + f * 16 + rq + rr;
            float* prow = pf + (size_t)(Mbase + rloc) * HDIM + wn * 128 + fm;
            float s = 0.0f;
            #pragma unroll
            for (int g = 0; g < 8; ++g) {
                const float val = acc[f][g][rr];
                __builtin_nontemporal_store(val, &prow[g * 16]);
                s += vv[g] * fast_tanh(val + pv[g]);
            }
            s += __shfl_xor(s, 1);
            s += __shfl_xor(s, 2);
            s += __shfl_xor(s, 4);
            s += __shfl_xor(s, 8);
            if (fm == 0) uls[rloc * 4 + wn] = s;
        }
    }
    __syncthreads();
    if (t < 128) {
        const float4 p4 = *(const float4*)(uls + t * 4);
        const float u = p4.x + p4.y + p4.z + p4.w;
        logits[Mbase + t] = 10.0f * fast_tanh(u);
    }
}

extern "C" void kernel_launch(void* const* d_in, const int* in_sizes, int n_in,
                              void* d_out, int out_size, void* d_ws, size_t ws_size,
                              hipStream_t stream) {
    const float* features = (const float*)d_in[0];
    const float* query    = (const float*)d_in[1];
    const float* Wf       = (const float*)d_in[2];
    const float* Wq       = (const float*)d_in[3];
    const float* v        = (const float*)d_in[4];

    float* pf     = (float*)d_out;
    float* logits = (float*)d_out + 33554432;

    float* ws_pq  = (float*)d_ws;                    // 8192 f32  (32KB)
    short* ws_wbf = (short*)(ws_pq + 8192);          // 524288 bf16 (1MB)

    wfcvt_kernel<<<256, 256, 0, stream>>>(Wf, ws_wbf);
    pq_kernel<<<16, 512, 0, stream>>>(query, Wq, ws_pq);
    gemm_kernel<<<512, 512, 0, stream>>>(features, ws_wbf, ws_pq, v, pf, logits);
}

// Round 4
// 173.607 us; speedup vs baseline: 1.7220x; 1.7220x over previous
//
#include <hip/hip_runtime.h>
#include <hip/hip_bf16.h>
#include <stdint.h>

// B=16, N=4096, H=512, K=2H=1024
//   pf[b,n,h]   = sum_k features[b,n,k] * Wf[h,k]
//   pq[b,h]     = sum_k query[b,k] * Wq[h,k]
//   logits[b,n] = 10*tanh( sum_h v[h]*tanh(pf+pq) )
// Outputs: pf (33554432 f32) then logits (65536 f32).
// R4: decouple. B(Wf) pre-shuffled into MFMA-fragment order in ws (1MB,
// L2-resident, shared by all blocks) -> plain reg loads, zero barriers.
// A staged fp32 via global_load_lds (inverse-swizzled source, linear LDS),
// TRIPLE-buffered 8KB tiles -> exactly ONE s_barrier + one counted
// s_waitcnt vmcnt(10) per K-step (safe: stage k+2 never hits a live buffer).
// 256-thr blocks (4 waves in n), wave tile 64x128, fp32->bf16 on LDS read.

#define KDIM 1024
#define HDIM 512

typedef short bf16x8 __attribute__((ext_vector_type(8)));
typedef float f32x4  __attribute__((ext_vector_type(4)));

__device__ __forceinline__ float fast_tanh(float x) {
    float ax = fabsf(x);
    float e  = __expf(-2.0f * ax);
    float r  = (1.0f - e) / (1.0f + e);
    return copysignf(r, x);
}

__device__ __forceinline__ short f2bf(float x) {
    __hip_bfloat16 b = __float2bfloat16(x);
    return (short)__builtin_bit_cast(unsigned short, b);
}

__device__ __forceinline__ bf16x8 cvt8(float4 a, float4 b) {
    bf16x8 o;
    o[0] = f2bf(a.x); o[1] = f2bf(a.y); o[2] = f2bf(a.z); o[3] = f2bf(a.w);
    o[4] = f2bf(b.x); o[5] = f2bf(b.y); o[6] = f2bf(b.z); o[7] = f2bf(b.w);
    return o;
}

// ---------------- Wf -> bf16 MFMA-fragment order ----------------
// chunk index tid = (kt*32 + gg)*64 + lane, lane = fkg*16 + fm.
// content = Wf[col = gg*16+fm][kt*32 + fkg*8 .. +8] as bf16x8.
__global__ void bshuf_kernel(const float* __restrict__ Wf, short* __restrict__ Bsh) {
    const int tid = blockIdx.x * 256 + threadIdx.x;   // 0..65535
    const int kt  = tid >> 11;
    const int gg  = (tid >> 6) & 31;
    const int ln  = tid & 63;
    const int fm  = ln & 15, fkg = ln >> 4;
    const int col = gg * 16 + fm;
    const int k0  = kt * 32 + fkg * 8;
    const float* src = Wf + col * KDIM + k0;
    float4 a = *(const float4*)src;
    float4 b = *(const float4*)(src + 4);
    *(bf16x8*)(Bsh + (size_t)tid * 8) = cvt8(a, b);
}

// ---------------- tiny GEMM: pq[b,h] ----------------
__global__ void pq_kernel(const float* __restrict__ query,
                          const float* __restrict__ Wq,
                          float* __restrict__ pq) {
    const int t = blockIdx.x * blockDim.x + threadIdx.x;   // 8192
    const int b = t >> 9, h = t & 511;
    const float4* q  = (const float4*)(query + (b << 9));
    const float4* wq = (const float4*)(Wq + ((size_t)h << 9));
    float s = 0.0f;
    #pragma unroll 4
    for (int i = 0; i < 128; ++i) {
        float4 a = q[i], c = wq[i];
        s += a.x * c.x + a.y * c.y + a.z * c.z + a.w * c.w;
    }
    pq[t] = s;
}

// ---------------- main GEMM + fused epilogue ----------------
// 256 threads = 4 waves (all in n). Block tile 64 x 512, BK=32, 32 K-steps.
__global__ __launch_bounds__(256, 2) void gemm_kernel(
    const float* __restrict__ A, const short* __restrict__ Bsh,
    const float* __restrict__ pq, const float* __restrict__ v,
    float* __restrict__ pf, float* __restrict__ logits)
{
    __shared__ __align__(16) char ldsA[3][8192];   // 64 rows x 128B, fp32
    __shared__ float uls[256];                     // 64 rows x 4 waves
    const int t    = threadIdx.x;
    const int lane = t & 63;
    const int w    = t >> 6;          // wave = n-group (cols w*128..+128)
    const int fm   = lane & 15;
    const int fkg  = lane >> 4;       // k subgroup
    const int Mbase = blockIdx.x * 64;

    // ---- A stage: inverse-swizzled global sources, linear LDS dest ----
    // LDS[row][slot] holds global chunk (row, slot ^ (row&7)); 16B chunks.
    int asrc[2], adst[2];
    #pragma unroll
    for (int i = 0; i < 2; ++i) {
        const int idx  = w * 128 + i * 64 + lane;   // 0..511
        const int row  = idx >> 3;
        const int slot = idx & 7;
        asrc[i] = row * 4096 + ((slot ^ (row & 7)) << 4);
        adst[i] = (w * 2 + i) * 1024;
    }
    const char* Ab = (const char*)(A + (size_t)Mbase * KDIM);
    const char* Bb = (const char*)Bsh + ((size_t)(w * 8 * 64) + lane) * 16;

    // ---- A fragment read offsets (swizzled) ----
    int ard[4][2];
    #pragma unroll
    for (int f = 0; f < 4; ++f) {
        const int r = f * 16 + fm, c0 = fkg * 2;
        ard[f][0] = r * 128 + (((c0    ) ^ (r & 7)) << 4);
        ard[f][1] = r * 128 + (((c0 + 1) ^ (r & 7)) << 4);
    }

    f32x4 acc[4][8];
    const f32x4 zf = {0.0f, 0.0f, 0.0f, 0.0f};
    #pragma unroll
    for (int f = 0; f < 4; ++f)
        #pragma unroll
        for (int g = 0; g < 8; ++g) acc[f][g] = zf;

    #define STAGE(BUF, KT) do {                                              \
        _Pragma("unroll")                                                    \
        for (int i = 0; i < 2; ++i)                                          \
            __builtin_amdgcn_global_load_lds(                                \
                (const __attribute__((address_space(1))) void*)              \
                    (Ab + asrc[i] + (((KT) & 31) * 128)),                    \
                (__attribute__((address_space(3))) void*)                    \
                    (&ldsA[BUF][adst[i]]),                                   \
                16, 0, 0);                                                   \
    } while (0)

    STAGE(0, 0);

    bf16x8 bfr[8], abf[4];
    int rb = 0, wb = 1;
    #pragma unroll 1
    for (int kt = 0; kt < 32; ++kt) {
        // B frags for this step (L2-hot, no staging)
        const char* bk = Bb + kt * 32768;
        #pragma unroll
        for (int g = 0; g < 8; ++g)
            bfr[g] = *(const bf16x8*)(bk + g * 1024);
        // stage A for kt+1 (kt=31 stages a wrapped, in-bounds dummy)
        STAGE(wb, kt + 1);
        // A(kt) gll are the 2 oldest of [gll_kt(2), B_kt(8), gll_kt+1(2)]
        asm volatile("s_waitcnt vmcnt(10)" ::: "memory");
        __builtin_amdgcn_s_barrier();
        asm volatile("" ::: "memory");
        const char* base = ldsA[rb];
        #pragma unroll
        for (int f = 0; f < 4; ++f)
            abf[f] = cvt8(*(const float4*)(base + ard[f][0]),
                          *(const float4*)(base + ard[f][1]));
        #pragma unroll
        for (int f = 0; f < 4; ++f)
            #pragma unroll
            for (int g = 0; g < 8; ++g)
                acc[f][g] = __builtin_amdgcn_mfma_f32_16x16x32_bf16(
                    abf[f], bfr[g], acc[f][g], 0, 0, 0);
        rb = (rb == 2) ? 0 : rb + 1;
        wb = (wb == 2) ? 0 : wb + 1;
    }
    #undef STAGE

    __syncthreads();

    // ---- fused epilogue ----
    const int bidx = Mbase >> 12;
    const float* pqb = pq + (bidx << 9);
    float vv[8], pv[8];
    #pragma unroll
    for (int g = 0; g < 8; ++g) {
        const int c = w * 128 + g * 16 + fm;
        vv[g] = v[c];
        pv[g] = pqb[c];
    }
    #pragma unroll
    for (int f = 0; f < 4; ++f) {
        #pragma unroll
        for (int rr = 0; rr < 4; ++rr) {
            const int rloc = f * 16 + fkg * 4 + rr;
            float* prow = pf + (size_t)(Mbase + rloc) * HDIM + w * 128 + fm;
            float s = 0.0f;
            #pragma unroll
            for (int g = 0; g < 8; ++g) {
                const float val = acc[f][g][rr];
                __builtin_nontemporal_store(val, &prow[g * 16]);
                s += vv[g] * fast_tanh(val + pv[g]);
            }
            s += __shfl_xor(s, 1);
            s += __shfl_xor(s, 2);
            s += __shfl_xor(s, 4);
            s += __shfl_xor(s, 8);
            if (fm == 0) uls[rloc * 4 + w] = s;
        }
    }
    __syncthreads();
    if (t < 64) {
        const float4 p4 = *(const float4*)(uls + t * 4);
        const float u = p4.x + p4.y + p4.z + p4.w;
        logits[Mbase + t] = 10.0f * fast_tanh(u);
    }
}

extern "C" void kernel_launch(void* const* d_in, const int* in_sizes, int n_in,
                              void* d_out, int out_size, void* d_ws, size_t ws_size,
                              hipStream_t stream) {
    const float* features = (const float*)d_in[0];
    const float* query    = (const float*)d_in[1];
    const float* Wf       = (const float*)d_in[2];
    const float* Wq       = (const float*)d_in[3];
    const float* v        = (const float*)d_in[4];

    float* pf     = (float*)d_out;
    float* logits = (float*)d_out + 33554432;

    float* ws_pq  = (float*)d_ws;                    // 8192 f32  (32KB)
    short* ws_bsh = (short*)(ws_pq + 8192);          // 524288 bf16 (1MB)

    bshuf_kernel<<<256, 256, 0, stream>>>(Wf, ws_bsh);
    pq_kernel<<<16, 512, 0, stream>>>(query, Wq, ws_pq);
    gemm_kernel<<<1024, 256, 0, stream>>>(features, ws_bsh, ws_pq, v, pf, logits);
}